// Round 19
// baseline (53.144 us; speedup 1.0000x reference)
//
#include <hip/hip_runtime.h>

#define B_   8
#define S_   1024
#define D_   512
#define H_   8
#define HD_  64
#define NT_  (B_ * S_)                    // 8192 tokens
#define QSCALE_ 0.06376387f               // (1/sqrt(512)) * log2(e)
#define C4_    5.7707802f                 // 4 * log2(e)

typedef _Float16 f16;
typedef _Float16 f16x2 __attribute__((ext_vector_type(2)));
typedef _Float16 f16x4 __attribute__((ext_vector_type(4)));
typedef _Float16 f16x8 __attribute__((ext_vector_type(8)));
typedef float    f32x4 __attribute__((ext_vector_type(4)));

#define GLOAD_LDS16(g, l) \
    __builtin_amdgcn_global_load_lds( \
        (const __attribute__((address_space(1))) unsigned int*)(g), \
        (__attribute__((address_space(3))) unsigned int*)(l), 16, 0, 0)

#define MFMA16(a, b, c) __builtin_amdgcn_mfma_f32_16x16x32_f16(a, b, c, 0, 0, 0)

#define CVT_PK(p0, p1) __builtin_bit_cast(f16x2, __builtin_amdgcn_cvt_pkrtz(p0, p1))

// Tiled operand layout (shared by prep + gemm):
//   kt-block(tile,kt) is 4096 f16 = 8KB: offset = c*1024 + r*8 + e
//     (r=row%128, c=(k%32)/8, e=k%8)
//   A: xh_t[(mtile*16+kt)*4096+...]  B: Bt_t[(ntile*16+kt)*4096+...]

// ---------------------------------------------------------------------------
// prep_fused: blocks [0,1024): cast x fp32 -> f16 in tiled layout.
//             blocks [1024,1216): Bt_t = (Wc_g+Wp_g)^T f16 in tiled layout.
// ---------------------------------------------------------------------------
__global__ __launch_bounds__(256) void prep_fused(
    const float* __restrict__ x, f16* __restrict__ xh_t,
    const float* __restrict__ Wcq, const float* __restrict__ Wck, const float* __restrict__ Wcv,
    const float* __restrict__ Wpq, const float* __restrict__ Wpk, const float* __restrict__ Wpv,
    f16* __restrict__ Bt_t)
{
    __shared__ float tile[64][68];
    const int tid = threadIdx.x;

    if (blockIdx.x < 1024) {
        const int mtile = blockIdx.x >> 4;
        const int ktile = blockIdx.x & 15;
        f16* dst = xh_t + ((size_t)mtile * 16 + ktile) * 4096;
#pragma unroll
        for (int half = 0; half < 2; ++half) {
            const int q = half * 256 + tid;       // 0..511
            const int r = q >> 2;                 // 0..127
            const int c = q & 3;                  // 0..3
            const float* src = x + (size_t)(mtile * 128 + r) * D_ + ktile * 32 + c * 8;
            float4 a = *(const float4*)(src);
            float4 b = *(const float4*)(src + 4);
            f16x8 o = { (f16)a.x, (f16)a.y, (f16)a.z, (f16)a.w,
                        (f16)b.x, (f16)b.y, (f16)b.z, (f16)b.w };
            *(f16x8*)(dst + c * 1024 + r * 8) = o;
        }
        return;
    }

    const int wk = blockIdx.x - 1024;        // 0..191
    const int k0 = (wk & 7) * 64;
    const int n0 = (wk >> 3) * 64;           // 0..1472
    const int g  = n0 >> 9;
    const int c0 = n0 & 511;
    const float* Wc = (g == 0) ? Wcq : (g == 1) ? Wck : Wcv;
    const float* Wp = (g == 0) ? Wpq : (g == 1) ? Wpk : Wpv;

#pragma unroll
    for (int it = 0; it < 4; ++it) {
        int row = it * 16 + (tid >> 4);
        int c4  = (tid & 15) * 4;
        float4 a = *(const float4*)(Wc + (size_t)(k0 + row) * D_ + c0 + c4);
        float4 b = *(const float4*)(Wp + (size_t)(k0 + row) * D_ + c0 + c4);
        tile[row][c4 + 0] = a.x + b.x;
        tile[row][c4 + 1] = a.y + b.y;
        tile[row][c4 + 2] = a.z + b.z;
        tile[row][c4 + 3] = a.w + b.w;
    }
    __syncthreads();

    const int ntile = n0 >> 7;
    const int rbase = n0 & 64;
#pragma unroll
    for (int it = 0; it < 2; ++it) {
        int nr = it * 32 + (tid >> 3);        // 0..63
        int kc = (tid & 7) * 8;               // 0..56
        f16x8 o;
#pragma unroll
        for (int j = 0; j < 8; ++j) o[j] = (f16)tile[kc + j][nr];
        const int kt = (k0 + kc) >> 5;
        const int c  = (kc >> 3) & 3;
        const int r  = rbase + nr;
        *(f16x8*)(Bt_t + ((size_t)ntile * 16 + kt) * 4096 + c * 1024 + r * 8) = o;
    }
}

// ---------------------------------------------------------------------------
// QKV GEMM: 128x128 tile, BK=32 — exact round-7 structure (best passing).
//   Kws element (s,d): tile=s>>6, r=s&63: r*64 + (((d>>3)^(r&7))<<3) + (d&7)
//   Vws element (s,d): tile=s>>6, c=s&63: d*64 + (((c>>3)^(d&7))<<3) + (c&7)
// ---------------------------------------------------------------------------
__global__ __launch_bounds__(256) void qkv_gemm(
    const f16* __restrict__ xh_t, const f16* __restrict__ Bt_t,
    const float* __restrict__ bcq, const float* __restrict__ bck, const float* __restrict__ bcv,
    const float* __restrict__ bpq, const float* __restrict__ bpk, const float* __restrict__ bpv,
    f16* __restrict__ Qh, f16* __restrict__ Kws, f16* __restrict__ Vws)
{
    __shared__ __align__(16) char smem_raw[36864];   // 2 x (8KB A | 8KB B); Cs reuse

    const int bid   = blockIdx.x;
    const int xcd   = bid & 7;
    const int idx   = bid >> 3;                 // 0..95
    const int mtile = xcd * 8 + (idx & 7);      // 0..63
    const int ntile = idx >> 3;                 // 0..11
    const int m0 = mtile * 128;
    const int n0 = ntile * 128;

    const int tid  = threadIdx.x;
    const int lane = tid & 63;
    const int wave = tid >> 6;
    const int wr = wave >> 1, wc = wave & 1;
    const int lo4 = lane & 15, hi4 = lane >> 4;

    const f16* gA = xh_t + (size_t)mtile * 16 * 4096;
    const f16* gB = Bt_t + (size_t)ntile * 16 * 4096;

#define STAGE(bufsel, kt) do { \
        f16* _A = (f16*)(smem_raw + (bufsel) * 16384); \
        f16* _B = (f16*)(smem_raw + (bufsel) * 16384 + 8192); \
        GLOAD_LDS16(gA + (kt) * 4096 + tid * 8,         _A + tid * 8);         \
        GLOAD_LDS16(gA + (kt) * 4096 + (tid + 256) * 8, _A + (tid + 256) * 8); \
        GLOAD_LDS16(gB + (kt) * 4096 + tid * 8,         _B + tid * 8);         \
        GLOAD_LDS16(gB + (kt) * 4096 + (tid + 256) * 8, _B + (tid + 256) * 8); \
    } while (0)

    f32x4 acc[4][4];
#pragma unroll
    for (int i = 0; i < 4; ++i)
#pragma unroll
        for (int j = 0; j < 4; ++j) acc[i][j] = (f32x4){0.f, 0.f, 0.f, 0.f};

    STAGE(0, 0);
    asm volatile("s_waitcnt vmcnt(0)" ::: "memory");
    __syncthreads();

    for (int t = 0; t < 16; ++t) {
        const int cur = t & 1;
        if (t < 15) STAGE(cur ^ 1, t + 1);

        const f16* Ab = (const f16*)(smem_raw + cur * 16384);
        const f16* Bb = (const f16*)(smem_raw + cur * 16384 + 8192);
        f16x8 a[4], b[4];
#pragma unroll
        for (int i = 0; i < 4; ++i)
            a[i] = *(const f16x8*)(Ab + hi4 * 1024 + (wr * 64 + i * 16 + lo4) * 8);
#pragma unroll
        for (int j = 0; j < 4; ++j)
            b[j] = *(const f16x8*)(Bb + hi4 * 1024 + (wc * 64 + j * 16 + lo4) * 8);
#pragma unroll
        for (int i = 0; i < 4; ++i)
#pragma unroll
            for (int j = 0; j < 4; ++j)
                acc[i][j] = MFMA16(a[i], b[j], acc[i][j]);

        asm volatile("s_waitcnt vmcnt(0)" ::: "memory");
        __syncthreads();
    }
#undef STAGE

    // ---- epilogue: wave-private 64x64 region -> LDS -> coalesced stores ----
    const int g = n0 >> 9;
    const float* bc = (g == 0) ? bcq : (g == 1) ? bck : bcv;
    const float* bp = (g == 0) ? bpq : (g == 1) ? bpk : bpv;

    const int colb = n0 + wc * 64;         // 64-aligned -> head uniform per wave
    const int h    = (colb & 511) >> 6;
    const int rowb = m0 + wr * 64;         // 64-aligned within one b
    const int bb   = rowb >> 10;
    const int s0   = rowb & 1023;

    float bias[4];
#pragma unroll
    for (int j = 0; j < 4; ++j) {
        const int cg = (colb + j * 16 + lo4) & 511;
        bias[j] = bc[cg] + bp[cg];
    }

    f16* Cs = (f16*)smem_raw + wave * 4608;     // [64][72] f16 per wave
    const size_t bhbase = (size_t)(bb * H_ + h) * 65536;

    if (g == 2) {
        // V: LDS transposed CsT[d][s_local]; vectorized f16x4 writes
#pragma unroll
        for (int i = 0; i < 4; ++i)
#pragma unroll
            for (int j = 0; j < 4; ++j) {
                f16x4 v = { (f16)(acc[i][j][0] + bias[j]), (f16)(acc[i][j][1] + bias[j]),
                            (f16)(acc[i][j][2] + bias[j]), (f16)(acc[i][j][3] + bias[j]) };
                *(f16x4*)(Cs + (j * 16 + lo4) * 72 + i * 16 + hi4 * 4) = v;
            }
        asm volatile("s_waitcnt lgkmcnt(0)" ::: "memory");
        __builtin_amdgcn_sched_barrier(0);
        const size_t tbase = bhbase + (size_t)(s0 >> 6) * 4096;
#pragma unroll
        for (int it = 0; it < 8; ++it) {
            const int d  = it * 8 + (lane >> 3);
            const int cs = lane & 7;
            f16x8 chunk = *(const f16x8*)(Cs + d * 72 + cs * 8);
            *(f16x8*)(Vws + tbase + d * 64 + ((cs ^ (d & 7)) << 3)) = chunk;
        }
    } else {
        // Q/K: row-major Cs[s_local][d]; scalar writes, vector chunk reads
        const float scale = (g == 0) ? QSCALE_ : 1.f;
#pragma unroll
        for (int i = 0; i < 4; ++i)
#pragma unroll
            for (int j = 0; j < 4; ++j)
#pragma unroll
                for (int r = 0; r < 4; ++r)
                    Cs[(i * 16 + hi4 * 4 + r) * 72 + j * 16 + lo4] =
                        (f16)((acc[i][j][r] + bias[j]) * scale);
        asm volatile("s_waitcnt lgkmcnt(0)" ::: "memory");
        __builtin_amdgcn_sched_barrier(0);
#pragma unroll
        for (int it = 0; it < 8; ++it) {
            const int rr = it * 8 + (lane >> 3);
            const int ci = lane & 7;
            f16x8 chunk = *(const f16x8*)(Cs + rr * 72 + ci * 8);
            if (g == 0) {
                *(f16x8*)(Qh + bhbase + (size_t)(s0 + rr) * 64 + ci * 8) = chunk;
            } else {
                const size_t tbase = bhbase + (size_t)(s0 >> 6) * 4096;
                *(f16x8*)(Kws + tbase + rr * 64 + ((ci ^ (rr & 7)) << 3)) = chunk;
            }
        }
    }
}

// ---------------------------------------------------------------------------
// Attention: R17 512-thread structure with DOUBLED TLP: grid 512 = 64 bh x
// 8 q-tiles (wave owns 16 q-rows, qg collapsed), KVBLK=64, LDS ~51KB ->
// 2 blocks/CU = 4 waves/SIMD (was grid-limited at 1 block/CU). R11's TLP
// failure drivers are absent: T14 reg staging (no DMA drain), 512-thread
// shared staging, packed P-stash. Extra L2 staging traffic ~3.7us aggregate.
// ---------------------------------------------------------------------------
__global__ __launch_bounds__(512) void attn_fwd(
    const f16* __restrict__ Qh, const f16* __restrict__ Kws,
    const f16* __restrict__ Vws, float* __restrict__ out)
{
    __shared__ __align__(16) f16 Ks[2][4096];
    __shared__ __align__(16) f16 Vs[2][4096];
    __shared__ __align__(16) f16 Ps[8][16 * 72];
    __shared__ float Lw[8][16];

    const int b0 = blockIdx.x;                       // 0..511
    const int bh = (b0 & 7) * 8 + ((b0 >> 3) & 7);   // same bh -> same XCD
    const int qt = b0 >> 6;                          // 0..7

    const int wave = threadIdx.x >> 6;               // 0..7
    const int lane = threadIdx.x & 63;
    const int lo4 = lane & 15, hi4 = lane >> 4;
    const int q0 = qt * 128 + wave * 16;

    const f16* Qp = Qh  + (size_t)bh * 65536;
    const f16* Kp = Kws + (size_t)bh * 65536;
    const f16* Vp = Vws + (size_t)bh * 65536;
    f16* Pw = &Ps[wave][0];

    f16x8 aq[2];
#pragma unroll
    for (int hh = 0; hh < 2; ++hh)
        aq[hh] = *(const f16x8*)(Qp + (q0 + lo4) * 64 + hh * 32 + hi4 * 8);

    f32x4 o[4];
    float l = 0.f;
#pragma unroll
    for (int dt = 0; dt < 4; ++dt)
        o[dt] = (f32x4){0.f, 0.f, 0.f, 0.f};

    const int soff = threadIdx.x * 8;    // 512 thr x 8 f16 = full 4096-f16 tile

    // prologue: tile 0 via regs -> LDS (one K + one V load per thread)
    {
        f16x8 ka = *(const f16x8*)(Kp + soff);
        f16x8 va = *(const f16x8*)(Vp + soff);
        *(f16x8*)(&Ks[0][soff]) = ka;
        *(f16x8*)(&Vs[0][soff]) = va;
    }
    __syncthreads();

    for (int t = 0; t < 16; ++t) {
        const int cur = t & 1;

        // T14 issue-early: next tile -> registers (no consumer until bottom)
        f16x8 kna, vna;
        if (t < 15) {
            kna = *(const f16x8*)(Kp + (t + 1) * 4096 + soff);
            vna = *(const f16x8*)(Vp + (t + 1) * 4096 + soff);
        }

        const f16* Kc = &Ks[cur][0];
        const f16* Vc = &Vs[cur][0];

        // Swapped QK^T: sc = K_frag (A) x Q_frag (B). Lane: query = lo4,
        // keys = f*16 + hi4*4 + {0..3} (consecutive) -> packed b64 stash.
#pragma unroll
        for (int f = 0; f < 4; ++f) {
            const int c = f * 16 + lo4;                 // key row for K read
            f16x8 bk0 = *(const f16x8*)(Kc + c * 64 + ((hi4 ^ (c & 7)) << 3));
            f16x8 bk1 = *(const f16x8*)(Kc + c * 64 + (((4 + hi4) ^ (c & 7)) << 3));
            f32x4 sc = (f32x4){0.f, 0.f, 0.f, 0.f};
            sc = MFMA16(bk0, aq[0], sc);
            sc = MFMA16(bk1, aq[1], sc);
            float p0 = __builtin_amdgcn_exp2f(sc[0] - C4_);
            float p1 = __builtin_amdgcn_exp2f(sc[1] - C4_);
            float p2 = __builtin_amdgcn_exp2f(sc[2] - C4_);
            float p3 = __builtin_amdgcn_exp2f(sc[3] - C4_);
            l += (p0 + p1) + (p2 + p3);
            f16x2 a01 = CVT_PK(p0, p1);
            f16x2 a23 = CVT_PK(p2, p3);
            f16x4 pv = { a01[0], a01[1], a23[0], a23[1] };
            *(f16x4*)(Pw + lo4 * 72 + f * 16 + hi4 * 4) = pv;
        }
        asm volatile("s_waitcnt lgkmcnt(0)" ::: "memory");
        __builtin_amdgcn_sched_barrier(0);

        // PV: o += P @ V   (P read as A-frag; V rows = d, swizzled cols = keys)
        f16x8 ap0 = *(const f16x8*)(Pw + lo4 * 72 + hi4 * 8);
        f16x8 ap1 = *(const f16x8*)(Pw + lo4 * 72 + 32 + hi4 * 8);
#pragma unroll
        for (int dt = 0; dt < 4; ++dt) {
            const int d = dt * 16 + lo4;
            f16x8 bv0 = *(const f16x8*)(Vc + d * 64 + ((hi4 ^ (d & 7)) << 3));
            f16x8 bv1 = *(const f16x8*)(Vc + d * 64 + (((4 + hi4) ^ (d & 7)) << 3));
            o[dt] = MFMA16(ap0, bv0, o[dt]);
            o[dt] = MFMA16(ap1, bv1, o[dt]);
        }

        // T14 write-late: registers -> other LDS buffer
        if (t < 15) {
            *(f16x8*)(&Ks[cur ^ 1][soff]) = kna;
            *(f16x8*)(&Vs[cur ^ 1][soff]) = vna;
        }
        __syncthreads();
    }

    // reduce l across the 4 hi4 groups (query = lo4 per lane)
    l += __shfl_xor(l, 16);
    l += __shfl_xor(l, 32);
    // transpose l to PV output rows via per-wave LDS
    if (lane < 16) Lw[wave][lane] = l;
    asm volatile("s_waitcnt lgkmcnt(0)" ::: "memory");
    __builtin_amdgcn_sched_barrier(0);

    const int b = bh >> 3;
    const int h = bh & 7;
#pragma unroll
    for (int r = 0; r < 4; ++r) {
        const float inv = 1.f / Lw[wave][hi4 * 4 + r];
        const int s_idx = q0 + hi4 * 4 + r;
        float* op = out + ((size_t)(b * S_ + s_idx)) * D_ + h * HD_;
#pragma unroll
        for (int dt = 0; dt < 4; ++dt)
            op[dt * 16 + lo4] = o[dt][r] * inv;
    }
}

// ---------------------------------------------------------------------------
extern "C" void kernel_launch(void* const* d_in, const int* in_sizes, int n_in,
                              void* d_out, int out_size, void* d_ws, size_t ws_size,
                              hipStream_t stream)
{
    const float* x   = (const float*)d_in[0];
    const float* Wcq = (const float*)d_in[1];
    const float* bcq = (const float*)d_in[2];
    const float* Wck = (const float*)d_in[3];
    const float* bck = (const float*)d_in[4];
    const float* Wcv = (const float*)d_in[5];
    const float* bcv = (const float*)d_in[6];
    const float* Wpq = (const float*)d_in[7];
    const float* bpq = (const float*)d_in[8];
    const float* Wpk = (const float*)d_in[9];
    const float* bpk = (const float*)d_in[10];
    const float* Wpv = (const float*)d_in[11];
    const float* bpv = (const float*)d_in[12];

    f16* ws = (f16*)d_ws;
    f16* xh_t = ws;                                  // 64*16*4096
    f16* Bt_t = xh_t + (size_t)64 * 16 * 4096;       // 12*16*4096
    f16* Qh   = Bt_t + (size_t)12 * 16 * 4096;       // 64*65536
    f16* Kws  = Qh + (size_t)64 * 65536;
    f16* Vws  = Kws + (size_t)64 * 65536;
    float* o = (float*)d_out;

    prep_fused<<<1216, 256, 0, stream>>>(x, xh_t, Wcq, Wck, Wcv, Wpq, Wpk, Wpv, Bt_t);
    qkv_gemm<<<768, 256, 0, stream>>>(xh_t, Bt_t, bcq, bck, bcv, bpq, bpk, bpv,
                                      Qh, Kws, Vws);
    attn_fwd<<<512, 512, 0, stream>>>(Qh, Kws, Vws, o);
}

// Round 20
// 51.701 us; speedup vs baseline: 1.0279x; 1.0279x over previous
//
#include <hip/hip_runtime.h>

#define B_   8
#define S_   1024
#define D_   512
#define H_   8
#define HD_  64
#define NT_  (B_ * S_)                    // 8192 tokens
#define QSCALE_ 0.06376387f               // (1/sqrt(512)) * log2(e)
#define C4_    5.7707802f                 // 4 * log2(e)

typedef _Float16 f16;
typedef _Float16 f16x2 __attribute__((ext_vector_type(2)));
typedef _Float16 f16x4 __attribute__((ext_vector_type(4)));
typedef _Float16 f16x8 __attribute__((ext_vector_type(8)));
typedef float    f32x4 __attribute__((ext_vector_type(4)));

#define GLOAD_LDS16(g, l) \
    __builtin_amdgcn_global_load_lds( \
        (const __attribute__((address_space(1))) unsigned int*)(g), \
        (__attribute__((address_space(3))) unsigned int*)(l), 16, 0, 0)

#define MFMA16(a, b, c) __builtin_amdgcn_mfma_f32_16x16x32_f16(a, b, c, 0, 0, 0)

#define CVT_PK(p0, p1) __builtin_bit_cast(f16x2, __builtin_amdgcn_cvt_pkrtz(p0, p1))

// Tiled operand layout (shared by prep + gemm):
//   kt-block(tile,kt) is 4096 f16 = 8KB: offset = c*1024 + r*8 + e
//     (r=row%128, c=(k%32)/8, e=k%8)
//   A: xh_t[(mtile*16+kt)*4096+...]  B: Bt_t[(ntile*16+kt)*4096+...]

// ---------------------------------------------------------------------------
// prep_fused: blocks [0,1024): cast x fp32 -> f16 in tiled layout.
//             blocks [1024,1216): Bt_t = (Wc_g+Wp_g)^T f16 in tiled layout.
// ---------------------------------------------------------------------------
__global__ __launch_bounds__(256) void prep_fused(
    const float* __restrict__ x, f16* __restrict__ xh_t,
    const float* __restrict__ Wcq, const float* __restrict__ Wck, const float* __restrict__ Wcv,
    const float* __restrict__ Wpq, const float* __restrict__ Wpk, const float* __restrict__ Wpv,
    f16* __restrict__ Bt_t)
{
    __shared__ float tile[64][68];
    const int tid = threadIdx.x;

    if (blockIdx.x < 1024) {
        const int mtile = blockIdx.x >> 4;
        const int ktile = blockIdx.x & 15;
        f16* dst = xh_t + ((size_t)mtile * 16 + ktile) * 4096;
#pragma unroll
        for (int half = 0; half < 2; ++half) {
            const int q = half * 256 + tid;       // 0..511
            const int r = q >> 2;                 // 0..127
            const int c = q & 3;                  // 0..3
            const float* src = x + (size_t)(mtile * 128 + r) * D_ + ktile * 32 + c * 8;
            float4 a = *(const float4*)(src);
            float4 b = *(const float4*)(src + 4);
            f16x8 o = { (f16)a.x, (f16)a.y, (f16)a.z, (f16)a.w,
                        (f16)b.x, (f16)b.y, (f16)b.z, (f16)b.w };
            *(f16x8*)(dst + c * 1024 + r * 8) = o;
        }
        return;
    }

    const int wk = blockIdx.x - 1024;        // 0..191
    const int k0 = (wk & 7) * 64;
    const int n0 = (wk >> 3) * 64;           // 0..1472
    const int g  = n0 >> 9;
    const int c0 = n0 & 511;
    const float* Wc = (g == 0) ? Wcq : (g == 1) ? Wck : Wcv;
    const float* Wp = (g == 0) ? Wpq : (g == 1) ? Wpk : Wpv;

#pragma unroll
    for (int it = 0; it < 4; ++it) {
        int row = it * 16 + (tid >> 4);
        int c4  = (tid & 15) * 4;
        float4 a = *(const float4*)(Wc + (size_t)(k0 + row) * D_ + c0 + c4);
        float4 b = *(const float4*)(Wp + (size_t)(k0 + row) * D_ + c0 + c4);
        tile[row][c4 + 0] = a.x + b.x;
        tile[row][c4 + 1] = a.y + b.y;
        tile[row][c4 + 2] = a.z + b.z;
        tile[row][c4 + 3] = a.w + b.w;
    }
    __syncthreads();

    const int ntile = n0 >> 7;
    const int rbase = n0 & 64;
#pragma unroll
    for (int it = 0; it < 2; ++it) {
        int nr = it * 32 + (tid >> 3);        // 0..63
        int kc = (tid & 7) * 8;               // 0..56
        f16x8 o;
#pragma unroll
        for (int j = 0; j < 8; ++j) o[j] = (f16)tile[kc + j][nr];
        const int kt = (k0 + kc) >> 5;
        const int c  = (kc >> 3) & 3;
        const int r  = rbase + nr;
        *(f16x8*)(Bt_t + ((size_t)ntile * 16 + kt) * 4096 + c * 1024 + r * 8) = o;
    }
}

// ---------------------------------------------------------------------------
// QKV GEMM: 128x128 tile, BK=32 — exact round-7 structure (best passing).
//   Kws element (s,d): tile=s>>6, r=s&63: r*64 + (((d>>3)^(r&7))<<3) + (d&7)
//   Vws element (s,d): tile=s>>6, c=s&63: d*64 + (((c>>3)^(d&7))<<3) + (c&7)
// ---------------------------------------------------------------------------
__global__ __launch_bounds__(256) void qkv_gemm(
    const f16* __restrict__ xh_t, const f16* __restrict__ Bt_t,
    const float* __restrict__ bcq, const float* __restrict__ bck, const float* __restrict__ bcv,
    const float* __restrict__ bpq, const float* __restrict__ bpk, const float* __restrict__ bpv,
    f16* __restrict__ Qh, f16* __restrict__ Kws, f16* __restrict__ Vws)
{
    __shared__ __align__(16) char smem_raw[36864];   // 2 x (8KB A | 8KB B); Cs reuse

    const int bid   = blockIdx.x;
    const int xcd   = bid & 7;
    const int idx   = bid >> 3;                 // 0..95
    const int mtile = xcd * 8 + (idx & 7);      // 0..63
    const int ntile = idx >> 3;                 // 0..11
    const int m0 = mtile * 128;
    const int n0 = ntile * 128;

    const int tid  = threadIdx.x;
    const int lane = tid & 63;
    const int wave = tid >> 6;
    const int wr = wave >> 1, wc = wave & 1;
    const int lo4 = lane & 15, hi4 = lane >> 4;

    const f16* gA = xh_t + (size_t)mtile * 16 * 4096;
    const f16* gB = Bt_t + (size_t)ntile * 16 * 4096;

#define STAGE(bufsel, kt) do { \
        f16* _A = (f16*)(smem_raw + (bufsel) * 16384); \
        f16* _B = (f16*)(smem_raw + (bufsel) * 16384 + 8192); \
        GLOAD_LDS16(gA + (kt) * 4096 + tid * 8,         _A + tid * 8);         \
        GLOAD_LDS16(gA + (kt) * 4096 + (tid + 256) * 8, _A + (tid + 256) * 8); \
        GLOAD_LDS16(gB + (kt) * 4096 + tid * 8,         _B + tid * 8);         \
        GLOAD_LDS16(gB + (kt) * 4096 + (tid + 256) * 8, _B + (tid + 256) * 8); \
    } while (0)

    f32x4 acc[4][4];
#pragma unroll
    for (int i = 0; i < 4; ++i)
#pragma unroll
        for (int j = 0; j < 4; ++j) acc[i][j] = (f32x4){0.f, 0.f, 0.f, 0.f};

    STAGE(0, 0);
    asm volatile("s_waitcnt vmcnt(0)" ::: "memory");
    __syncthreads();

    for (int t = 0; t < 16; ++t) {
        const int cur = t & 1;
        if (t < 15) STAGE(cur ^ 1, t + 1);

        const f16* Ab = (const f16*)(smem_raw + cur * 16384);
        const f16* Bb = (const f16*)(smem_raw + cur * 16384 + 8192);
        f16x8 a[4], b[4];
#pragma unroll
        for (int i = 0; i < 4; ++i)
            a[i] = *(const f16x8*)(Ab + hi4 * 1024 + (wr * 64 + i * 16 + lo4) * 8);
#pragma unroll
        for (int j = 0; j < 4; ++j)
            b[j] = *(const f16x8*)(Bb + hi4 * 1024 + (wc * 64 + j * 16 + lo4) * 8);
#pragma unroll
        for (int i = 0; i < 4; ++i)
#pragma unroll
            for (int j = 0; j < 4; ++j)
                acc[i][j] = MFMA16(a[i], b[j], acc[i][j]);

        asm volatile("s_waitcnt vmcnt(0)" ::: "memory");
        __syncthreads();
    }
#undef STAGE

    // ---- epilogue: wave-private 64x64 region -> LDS -> coalesced stores ----
    const int g = n0 >> 9;
    const float* bc = (g == 0) ? bcq : (g == 1) ? bck : bcv;
    const float* bp = (g == 0) ? bpq : (g == 1) ? bpk : bpv;

    const int colb = n0 + wc * 64;         // 64-aligned -> head uniform per wave
    const int h    = (colb & 511) >> 6;
    const int rowb = m0 + wr * 64;         // 64-aligned within one b
    const int bb   = rowb >> 10;
    const int s0   = rowb & 1023;

    float bias[4];
#pragma unroll
    for (int j = 0; j < 4; ++j) {
        const int cg = (colb + j * 16 + lo4) & 511;
        bias[j] = bc[cg] + bp[cg];
    }

    f16* Cs = (f16*)smem_raw + wave * 4608;     // [64][72] f16 per wave
    const size_t bhbase = (size_t)(bb * H_ + h) * 65536;

    if (g == 2) {
        // V: LDS transposed CsT[d][s_local]; vectorized f16x4 writes
#pragma unroll
        for (int i = 0; i < 4; ++i)
#pragma unroll
            for (int j = 0; j < 4; ++j) {
                f16x4 v = { (f16)(acc[i][j][0] + bias[j]), (f16)(acc[i][j][1] + bias[j]),
                            (f16)(acc[i][j][2] + bias[j]), (f16)(acc[i][j][3] + bias[j]) };
                *(f16x4*)(Cs + (j * 16 + lo4) * 72 + i * 16 + hi4 * 4) = v;
            }
        asm volatile("s_waitcnt lgkmcnt(0)" ::: "memory");
        __builtin_amdgcn_sched_barrier(0);
        const size_t tbase = bhbase + (size_t)(s0 >> 6) * 4096;
#pragma unroll
        for (int it = 0; it < 8; ++it) {
            const int d  = it * 8 + (lane >> 3);
            const int cs = lane & 7;
            f16x8 chunk = *(const f16x8*)(Cs + d * 72 + cs * 8);
            *(f16x8*)(Vws + tbase + d * 64 + ((cs ^ (d & 7)) << 3)) = chunk;
        }
    } else {
        // Q/K: row-major Cs[s_local][d]; scalar writes, vector chunk reads
        const float scale = (g == 0) ? QSCALE_ : 1.f;
#pragma unroll
        for (int i = 0; i < 4; ++i)
#pragma unroll
            for (int j = 0; j < 4; ++j)
#pragma unroll
                for (int r = 0; r < 4; ++r)
                    Cs[(i * 16 + hi4 * 4 + r) * 72 + j * 16 + lo4] =
                        (f16)((acc[i][j][r] + bias[j]) * scale);
        asm volatile("s_waitcnt lgkmcnt(0)" ::: "memory");
        __builtin_amdgcn_sched_barrier(0);
#pragma unroll
        for (int it = 0; it < 8; ++it) {
            const int rr = it * 8 + (lane >> 3);
            const int ci = lane & 7;
            f16x8 chunk = *(const f16x8*)(Cs + rr * 72 + ci * 8);
            if (g == 0) {
                *(f16x8*)(Qh + bhbase + (size_t)(s0 + rr) * 64 + ci * 8) = chunk;
            } else {
                const size_t tbase = bhbase + (size_t)(s0 >> 6) * 4096;
                *(f16x8*)(Kws + tbase + rr * 64 + ((ci ^ (rr & 7)) << 3)) = chunk;
            }
        }
    }
}

// ---------------------------------------------------------------------------
// Attention: best configuration (round 18). 512-thread blocks (8 waves),
// 256 blocks = 64 bh x 4 q-tiles, KVBLK=128: stage 16KB K + 16KB V per outer
// iteration (8 outer iters), two 64-key inner sub-steps on the staged halves
// (no barrier between; P-stash per-wave, same-wave DS ops program-ordered).
// T14 reg-staged double-buffering; swapped QK^T packed P-stash.
// ---------------------------------------------------------------------------
__global__ __launch_bounds__(512) void attn_fwd(
    const f16* __restrict__ Qh, const f16* __restrict__ Kws,
    const f16* __restrict__ Vws, float* __restrict__ out)
{
    __shared__ __align__(16) f16 Ks[2][8192];
    __shared__ __align__(16) f16 Vs[2][8192];
    __shared__ __align__(16) f16 Ps[8][32 * 72];
    __shared__ float Lw[8][32];

    const int b0 = blockIdx.x;                       // 0..255
    const int bh = (b0 & 7) * 8 + ((b0 >> 3) & 7);   // same bh -> same XCD
    const int qt = b0 >> 6;                          // 0..3

    const int wave = threadIdx.x >> 6;               // 0..7
    const int lane = threadIdx.x & 63;
    const int lo4 = lane & 15, hi4 = lane >> 4;
    const int q0 = qt * 256 + wave * 32;

    const f16* Qp = Qh  + (size_t)bh * 65536;
    const f16* Kp = Kws + (size_t)bh * 65536;
    const f16* Vp = Vws + (size_t)bh * 65536;
    f16* Pw = &Ps[wave][0];

    f16x8 aq[2][2];
#pragma unroll
    for (int qg = 0; qg < 2; ++qg)
#pragma unroll
        for (int hh = 0; hh < 2; ++hh)
            aq[qg][hh] = *(const f16x8*)(Qp + (q0 + qg * 16 + lo4) * 64 + hh * 32 + hi4 * 8);

    f32x4 o[2][4];
    float l[2] = {0.f, 0.f};
#pragma unroll
    for (int qg = 0; qg < 2; ++qg)
#pragma unroll
        for (int dt = 0; dt < 4; ++dt)
            o[qg][dt] = (f32x4){0.f, 0.f, 0.f, 0.f};

    const int soff = threadIdx.x * 8;    // 512 thr x 8 f16 = 4096 f16 per pass

    // prologue: tile 0 (16KB each) via regs -> LDS
    {
        f16x8 k0v = *(const f16x8*)(Kp + soff);
        f16x8 k1v = *(const f16x8*)(Kp + 4096 + soff);
        f16x8 v0v = *(const f16x8*)(Vp + soff);
        f16x8 v1v = *(const f16x8*)(Vp + 4096 + soff);
        *(f16x8*)(&Ks[0][soff])        = k0v;
        *(f16x8*)(&Ks[0][4096 + soff]) = k1v;
        *(f16x8*)(&Vs[0][soff])        = v0v;
        *(f16x8*)(&Vs[0][4096 + soff]) = v1v;
    }
    __syncthreads();

    for (int t = 0; t < 8; ++t) {
        const int cur = t & 1;

        // T14 issue-early: next 128-key tile -> registers
        f16x8 kn0, kn1, vn0, vn1;
        if (t < 7) {
            const f16* Kn = Kp + (t + 1) * 8192;
            const f16* Vn = Vp + (t + 1) * 8192;
            kn0 = *(const f16x8*)(Kn + soff);
            kn1 = *(const f16x8*)(Kn + 4096 + soff);
            vn0 = *(const f16x8*)(Vn + soff);
            vn1 = *(const f16x8*)(Vn + 4096 + soff);
        }

#pragma unroll
        for (int half = 0; half < 2; ++half) {
            const f16* Kc = &Ks[cur][half * 4096];
            const f16* Vc = &Vs[cur][half * 4096];

            // Swapped QK^T: sc = K_frag (A) x Q_frag (B). Lane: query = lo4,
            // keys = f*16 + hi4*4 + {0..3} (consecutive) -> packed b64 stash.
#pragma unroll
            for (int f = 0; f < 4; ++f) {
                const int c = f * 16 + lo4;                 // key row for K read
                f16x8 bk0 = *(const f16x8*)(Kc + c * 64 + ((hi4 ^ (c & 7)) << 3));
                f16x8 bk1 = *(const f16x8*)(Kc + c * 64 + (((4 + hi4) ^ (c & 7)) << 3));
#pragma unroll
                for (int qg = 0; qg < 2; ++qg) {
                    f32x4 sc = (f32x4){0.f, 0.f, 0.f, 0.f};
                    sc = MFMA16(bk0, aq[qg][0], sc);
                    sc = MFMA16(bk1, aq[qg][1], sc);
                    float p0 = __builtin_amdgcn_exp2f(sc[0] - C4_);
                    float p1 = __builtin_amdgcn_exp2f(sc[1] - C4_);
                    float p2 = __builtin_amdgcn_exp2f(sc[2] - C4_);
                    float p3 = __builtin_amdgcn_exp2f(sc[3] - C4_);
                    l[qg] += (p0 + p1) + (p2 + p3);
                    f16x2 a01 = CVT_PK(p0, p1);
                    f16x2 a23 = CVT_PK(p2, p3);
                    f16x4 pv = { a01[0], a01[1], a23[0], a23[1] };
                    *(f16x4*)(Pw + (qg * 16 + lo4) * 72 + f * 16 + hi4 * 4) = pv;
                }
            }
            asm volatile("s_waitcnt lgkmcnt(0)" ::: "memory");
            __builtin_amdgcn_sched_barrier(0);

            // PV: o += P @ V  (P read as A-frag; V rows = d, swizzled cols)
            f16x8 ap[2][2];
#pragma unroll
            for (int qg = 0; qg < 2; ++qg) {
                ap[qg][0] = *(const f16x8*)(Pw + (qg * 16 + lo4) * 72 + hi4 * 8);
                ap[qg][1] = *(const f16x8*)(Pw + (qg * 16 + lo4) * 72 + 32 + hi4 * 8);
            }
#pragma unroll
            for (int dt = 0; dt < 4; ++dt) {
                const int d = dt * 16 + lo4;
                f16x8 bv0 = *(const f16x8*)(Vc + d * 64 + ((hi4 ^ (d & 7)) << 3));
                f16x8 bv1 = *(const f16x8*)(Vc + d * 64 + (((4 + hi4) ^ (d & 7)) << 3));
#pragma unroll
                for (int qg = 0; qg < 2; ++qg) {
                    o[qg][dt] = MFMA16(ap[qg][0], bv0, o[qg][dt]);
                    o[qg][dt] = MFMA16(ap[qg][1], bv1, o[qg][dt]);
                }
            }
        }

        // T14 write-late: registers -> other LDS buffer
        if (t < 7) {
            *(f16x8*)(&Ks[cur ^ 1][soff])        = kn0;
            *(f16x8*)(&Ks[cur ^ 1][4096 + soff]) = kn1;
            *(f16x8*)(&Vs[cur ^ 1][soff])        = vn0;
            *(f16x8*)(&Vs[cur ^ 1][4096 + soff]) = vn1;
        }
        __syncthreads();
    }

    // reduce l across the 4 hi4 groups (query = qg*16 + lo4 per lane)
#pragma unroll
    for (int qg = 0; qg < 2; ++qg) {
        l[qg] += __shfl_xor(l[qg], 16);
        l[qg] += __shfl_xor(l[qg], 32);
    }
    // transpose l to PV output rows via per-wave LDS
    if (lane < 16) {
        Lw[wave][lane]      = l[0];
        Lw[wave][16 + lane] = l[1];
    }
    asm volatile("s_waitcnt lgkmcnt(0)" ::: "memory");
    __builtin_amdgcn_sched_barrier(0);

    const int b = bh >> 3;
    const int h = bh & 7;
#pragma unroll
    for (int qg = 0; qg < 2; ++qg)
#pragma unroll
        for (int r = 0; r < 4; ++r) {
            const float inv = 1.f / Lw[wave][qg * 16 + hi4 * 4 + r];
            const int s_idx = q0 + qg * 16 + hi4 * 4 + r;
            float* op = out + ((size_t)(b * S_ + s_idx)) * D_ + h * HD_;
#pragma unroll
            for (int dt = 0; dt < 4; ++dt)
                op[dt * 16 + lo4] = o[qg][dt][r] * inv;
        }
}

// ---------------------------------------------------------------------------
extern "C" void kernel_launch(void* const* d_in, const int* in_sizes, int n_in,
                              void* d_out, int out_size, void* d_ws, size_t ws_size,
                              hipStream_t stream)
{
    const float* x   = (const float*)d_in[0];
    const float* Wcq = (const float*)d_in[1];
    const float* bcq = (const float*)d_in[2];
    const float* Wck = (const float*)d_in[3];
    const float* bck = (const float*)d_in[4];
    const float* Wcv = (const float*)d_in[5];
    const float* bcv = (const float*)d_in[6];
    const float* Wpq = (const float*)d_in[7];
    const float* bpq = (const float*)d_in[8];
    const float* Wpk = (const float*)d_in[9];
    const float* bpk = (const float*)d_in[10];
    const float* Wpv = (const float*)d_in[11];
    const float* bpv = (const float*)d_in[12];

    f16* ws = (f16*)d_ws;
    f16* xh_t = ws;                                  // 64*16*4096
    f16* Bt_t = xh_t + (size_t)64 * 16 * 4096;       // 12*16*4096
    f16* Qh   = Bt_t + (size_t)12 * 16 * 4096;       // 64*65536
    f16* Kws  = Qh + (size_t)64 * 65536;
    f16* Vws  = Kws + (size_t)64 * 65536;
    float* o = (float*)d_out;

    prep_fused<<<1216, 256, 0, stream>>>(x, xh_t, Wcq, Wck, Wcv, Wpq, Wpk, Wpv, Bt_t);
    qkv_gemm<<<768, 256, 0, stream>>>(xh_t, Bt_t, bcq, bck, bcv, bpq, bpk, bpv,
                                      Qh, Kws, Vws);
    attn_fwd<<<256, 512, 0, stream>>>(Qh, Kws, Vws, o);
}

// Round 21
// 51.577 us; speedup vs baseline: 1.0304x; 1.0024x over previous
//
#include <hip/hip_runtime.h>

#define B_   8
#define S_   1024
#define D_   512
#define H_   8
#define HD_  64
#define NT_  (B_ * S_)                    // 8192 tokens
#define QSCALE_ 0.06376387f               // (1/sqrt(512)) * log2(e)
#define C4_    5.7707802f                 // 4 * log2(e)

typedef _Float16 f16;
typedef _Float16 f16x2 __attribute__((ext_vector_type(2)));
typedef _Float16 f16x4 __attribute__((ext_vector_type(4)));
typedef _Float16 f16x8 __attribute__((ext_vector_type(8)));
typedef float    f32x4 __attribute__((ext_vector_type(4)));

#define GLOAD_LDS16(g, l) \
    __builtin_amdgcn_global_load_lds( \
        (const __attribute__((address_space(1))) unsigned int*)(g), \
        (__attribute__((address_space(3))) unsigned int*)(l), 16, 0, 0)

#define MFMA16(a, b, c) __builtin_amdgcn_mfma_f32_16x16x32_f16(a, b, c, 0, 0, 0)

#define CVT_PK(p0, p1) __builtin_bit_cast(f16x2, __builtin_amdgcn_cvt_pkrtz(p0, p1))

// Tiled operand layout (shared by prep + gemm):
//   kt-block(tile,kt) is 4096 f16 = 8KB: offset = c*1024 + r*8 + e
//     (r=row%128, c=(k%32)/8, e=k%8)
//   A: xh_t[(mtile*16+kt)*4096+...]  B: Bt_t[(ntile*16+kt)*4096+...]

// ---------------------------------------------------------------------------
// prep_fused: blocks [0,1024): cast x fp32 -> f16 in tiled layout.
//             blocks [1024,1216): Bt_t = (Wc_g+Wp_g)^T f16 in tiled layout.
// ---------------------------------------------------------------------------
__global__ __launch_bounds__(256) void prep_fused(
    const float* __restrict__ x, f16* __restrict__ xh_t,
    const float* __restrict__ Wcq, const float* __restrict__ Wck, const float* __restrict__ Wcv,
    const float* __restrict__ Wpq, const float* __restrict__ Wpk, const float* __restrict__ Wpv,
    f16* __restrict__ Bt_t)
{
    __shared__ float tile[64][68];
    const int tid = threadIdx.x;

    if (blockIdx.x < 1024) {
        const int mtile = blockIdx.x >> 4;
        const int ktile = blockIdx.x & 15;
        f16* dst = xh_t + ((size_t)mtile * 16 + ktile) * 4096;
#pragma unroll
        for (int half = 0; half < 2; ++half) {
            const int q = half * 256 + tid;       // 0..511
            const int r = q >> 2;                 // 0..127
            const int c = q & 3;                  // 0..3
            const float* src = x + (size_t)(mtile * 128 + r) * D_ + ktile * 32 + c * 8;
            float4 a = *(const float4*)(src);
            float4 b = *(const float4*)(src + 4);
            f16x8 o = { (f16)a.x, (f16)a.y, (f16)a.z, (f16)a.w,
                        (f16)b.x, (f16)b.y, (f16)b.z, (f16)b.w };
            *(f16x8*)(dst + c * 1024 + r * 8) = o;
        }
        return;
    }

    const int wk = blockIdx.x - 1024;        // 0..191
    const int k0 = (wk & 7) * 64;
    const int n0 = (wk >> 3) * 64;           // 0..1472
    const int g  = n0 >> 9;
    const int c0 = n0 & 511;
    const float* Wc = (g == 0) ? Wcq : (g == 1) ? Wck : Wcv;
    const float* Wp = (g == 0) ? Wpq : (g == 1) ? Wpk : Wpv;

#pragma unroll
    for (int it = 0; it < 4; ++it) {
        int row = it * 16 + (tid >> 4);
        int c4  = (tid & 15) * 4;
        float4 a = *(const float4*)(Wc + (size_t)(k0 + row) * D_ + c0 + c4);
        float4 b = *(const float4*)(Wp + (size_t)(k0 + row) * D_ + c0 + c4);
        tile[row][c4 + 0] = a.x + b.x;
        tile[row][c4 + 1] = a.y + b.y;
        tile[row][c4 + 2] = a.z + b.z;
        tile[row][c4 + 3] = a.w + b.w;
    }
    __syncthreads();

    const int ntile = n0 >> 7;
    const int rbase = n0 & 64;
#pragma unroll
    for (int it = 0; it < 2; ++it) {
        int nr = it * 32 + (tid >> 3);        // 0..63
        int kc = (tid & 7) * 8;               // 0..56
        f16x8 o;
#pragma unroll
        for (int j = 0; j < 8; ++j) o[j] = (f16)tile[kc + j][nr];
        const int kt = (k0 + kc) >> 5;
        const int c  = (kc >> 3) & 3;
        const int r  = rbase + nr;
        *(f16x8*)(Bt_t + ((size_t)ntile * 16 + kt) * 4096 + c * 1024 + r * 8) = o;
    }
}

// ---------------------------------------------------------------------------
// QKV GEMM: 128x128 tile, BK=32 — round-7 structure (best passing).
//   Kws element (s,d): tile=s>>6, r=s&63: r*64 + (((d>>3)^(r&7))<<3) + (d&7)
//   Vws element (s,d): tile=s>>6, c=s&63: d*64 + (((c>>3)^(d&7))<<3) + (c&7)
// ---------------------------------------------------------------------------
__global__ __launch_bounds__(256) void qkv_gemm(
    const f16* __restrict__ xh_t, const f16* __restrict__ Bt_t,
    const float* __restrict__ bcq, const float* __restrict__ bck, const float* __restrict__ bcv,
    const float* __restrict__ bpq, const float* __restrict__ bpk, const float* __restrict__ bpv,
    f16* __restrict__ Qh, f16* __restrict__ Kws, f16* __restrict__ Vws)
{
    __shared__ __align__(16) char smem_raw[36864];   // 2 x (8KB A | 8KB B); Cs reuse

    const int bid   = blockIdx.x;
    const int xcd   = bid & 7;
    const int idx   = bid >> 3;                 // 0..95
    const int mtile = xcd * 8 + (idx & 7);      // 0..63
    const int ntile = idx >> 3;                 // 0..11
    const int m0 = mtile * 128;
    const int n0 = ntile * 128;

    const int tid  = threadIdx.x;
    const int lane = tid & 63;
    const int wave = tid >> 6;
    const int wr = wave >> 1, wc = wave & 1;
    const int lo4 = lane & 15, hi4 = lane >> 4;

    const f16* gA = xh_t + (size_t)mtile * 16 * 4096;
    const f16* gB = Bt_t + (size_t)ntile * 16 * 4096;

#define STAGE(bufsel, kt) do { \
        f16* _A = (f16*)(smem_raw + (bufsel) * 16384); \
        f16* _B = (f16*)(smem_raw + (bufsel) * 16384 + 8192); \
        GLOAD_LDS16(gA + (kt) * 4096 + tid * 8,         _A + tid * 8);         \
        GLOAD_LDS16(gA + (kt) * 4096 + (tid + 256) * 8, _A + (tid + 256) * 8); \
        GLOAD_LDS16(gB + (kt) * 4096 + tid * 8,         _B + tid * 8);         \
        GLOAD_LDS16(gB + (kt) * 4096 + (tid + 256) * 8, _B + (tid + 256) * 8); \
    } while (0)

    f32x4 acc[4][4];
#pragma unroll
    for (int i = 0; i < 4; ++i)
#pragma unroll
        for (int j = 0; j < 4; ++j) acc[i][j] = (f32x4){0.f, 0.f, 0.f, 0.f};

    STAGE(0, 0);
    asm volatile("s_waitcnt vmcnt(0)" ::: "memory");
    __syncthreads();

    for (int t = 0; t < 16; ++t) {
        const int cur = t & 1;
        if (t < 15) STAGE(cur ^ 1, t + 1);

        const f16* Ab = (const f16*)(smem_raw + cur * 16384);
        const f16* Bb = (const f16*)(smem_raw + cur * 16384 + 8192);
        f16x8 a[4], b[4];
#pragma unroll
        for (int i = 0; i < 4; ++i)
            a[i] = *(const f16x8*)(Ab + hi4 * 1024 + (wr * 64 + i * 16 + lo4) * 8);
#pragma unroll
        for (int j = 0; j < 4; ++j)
            b[j] = *(const f16x8*)(Bb + hi4 * 1024 + (wc * 64 + j * 16 + lo4) * 8);
#pragma unroll
        for (int i = 0; i < 4; ++i)
#pragma unroll
            for (int j = 0; j < 4; ++j)
                acc[i][j] = MFMA16(a[i], b[j], acc[i][j]);

        asm volatile("s_waitcnt vmcnt(0)" ::: "memory");
        __syncthreads();
    }
#undef STAGE

    // ---- epilogue: wave-private 64x64 region -> LDS -> coalesced stores ----
    const int g = n0 >> 9;
    const float* bc = (g == 0) ? bcq : (g == 1) ? bck : bcv;
    const float* bp = (g == 0) ? bpq : (g == 1) ? bpk : bpv;

    const int colb = n0 + wc * 64;         // 64-aligned -> head uniform per wave
    const int h    = (colb & 511) >> 6;
    const int rowb = m0 + wr * 64;         // 64-aligned within one b
    const int bb   = rowb >> 10;
    const int s0   = rowb & 1023;

    float bias[4];
#pragma unroll
    for (int j = 0; j < 4; ++j) {
        const int cg = (colb + j * 16 + lo4) & 511;
        bias[j] = bc[cg] + bp[cg];
    }

    f16* Cs = (f16*)smem_raw + wave * 4608;     // [64][72] f16 per wave
    const size_t bhbase = (size_t)(bb * H_ + h) * 65536;

    if (g == 2) {
        // V: LDS transposed CsT[d][s_local]; vectorized f16x4 writes
#pragma unroll
        for (int i = 0; i < 4; ++i)
#pragma unroll
            for (int j = 0; j < 4; ++j) {
                f16x4 v = { (f16)(acc[i][j][0] + bias[j]), (f16)(acc[i][j][1] + bias[j]),
                            (f16)(acc[i][j][2] + bias[j]), (f16)(acc[i][j][3] + bias[j]) };
                *(f16x4*)(Cs + (j * 16 + lo4) * 72 + i * 16 + hi4 * 4) = v;
            }
        asm volatile("s_waitcnt lgkmcnt(0)" ::: "memory");
        __builtin_amdgcn_sched_barrier(0);
        const size_t tbase = bhbase + (size_t)(s0 >> 6) * 4096;
#pragma unroll
        for (int it = 0; it < 8; ++it) {
            const int d  = it * 8 + (lane >> 3);
            const int cs = lane & 7;
            f16x8 chunk = *(const f16x8*)(Cs + d * 72 + cs * 8);
            *(f16x8*)(Vws + tbase + d * 64 + ((cs ^ (d & 7)) << 3)) = chunk;
        }
    } else {
        // Q/K: row-major Cs[s_local][d]; scalar writes, vector chunk reads
        const float scale = (g == 0) ? QSCALE_ : 1.f;
#pragma unroll
        for (int i = 0; i < 4; ++i)
#pragma unroll
            for (int j = 0; j < 4; ++j)
#pragma unroll
                for (int r = 0; r < 4; ++r)
                    Cs[(i * 16 + hi4 * 4 + r) * 72 + j * 16 + lo4] =
                        (f16)((acc[i][j][r] + bias[j]) * scale);
        asm volatile("s_waitcnt lgkmcnt(0)" ::: "memory");
        __builtin_amdgcn_sched_barrier(0);
#pragma unroll
        for (int it = 0; it < 8; ++it) {
            const int rr = it * 8 + (lane >> 3);
            const int ci = lane & 7;
            f16x8 chunk = *(const f16x8*)(Cs + rr * 72 + ci * 8);
            if (g == 0) {
                *(f16x8*)(Qh + bhbase + (size_t)(s0 + rr) * 64 + ci * 8) = chunk;
            } else {
                const size_t tbase = bhbase + (size_t)(s0 >> 6) * 4096;
                *(f16x8*)(Kws + tbase + rr * 64 + ((ci ^ (rr & 7)) << 3)) = chunk;
            }
        }
    }
}

// ---------------------------------------------------------------------------
// Attention: final configuration. 512-thread blocks (8 waves), 256 blocks =
// 64 bh x 4 q-tiles, KVBLK=128: stage 16KB K + 16KB V per outer iteration
// (8 outer iters), two 64-key inner sub-steps on the staged halves (no
// barrier between; P-stash per-wave, same-wave DS ops program-ordered).
// T14 reg-staged double-buffering; swapped QK^T packed P-stash.
// ---------------------------------------------------------------------------
__global__ __launch_bounds__(512) void attn_fwd(
    const f16* __restrict__ Qh, const f16* __restrict__ Kws,
    const f16* __restrict__ Vws, float* __restrict__ out)
{
    __shared__ __align__(16) f16 Ks[2][8192];
    __shared__ __align__(16) f16 Vs[2][8192];
    __shared__ __align__(16) f16 Ps[8][32 * 72];
    __shared__ float Lw[8][32];

    const int b0 = blockIdx.x;                       // 0..255
    const int bh = (b0 & 7) * 8 + ((b0 >> 3) & 7);   // same bh -> same XCD
    const int qt = b0 >> 6;                          // 0..3

    const int wave = threadIdx.x >> 6;               // 0..7
    const int lane = threadIdx.x & 63;
    const int lo4 = lane & 15, hi4 = lane >> 4;
    const int q0 = qt * 256 + wave * 32;

    const f16* Qp = Qh  + (size_t)bh * 65536;
    const f16* Kp = Kws + (size_t)bh * 65536;
    const f16* Vp = Vws + (size_t)bh * 65536;
    f16* Pw = &Ps[wave][0];

    f16x8 aq[2][2];
#pragma unroll
    for (int qg = 0; qg < 2; ++qg)
#pragma unroll
        for (int hh = 0; hh < 2; ++hh)
            aq[qg][hh] = *(const f16x8*)(Qp + (q0 + qg * 16 + lo4) * 64 + hh * 32 + hi4 * 8);

    f32x4 o[2][4];
    float l[2] = {0.f, 0.f};
#pragma unroll
    for (int qg = 0; qg < 2; ++qg)
#pragma unroll
        for (int dt = 0; dt < 4; ++dt)
            o[qg][dt] = (f32x4){0.f, 0.f, 0.f, 0.f};

    const int soff = threadIdx.x * 8;    // 512 thr x 8 f16 = 4096 f16 per pass

    // prologue: tile 0 (16KB each) via regs -> LDS
    {
        f16x8 k0v = *(const f16x8*)(Kp + soff);
        f16x8 k1v = *(const f16x8*)(Kp + 4096 + soff);
        f16x8 v0v = *(const f16x8*)(Vp + soff);
        f16x8 v1v = *(const f16x8*)(Vp + 4096 + soff);
        *(f16x8*)(&Ks[0][soff])        = k0v;
        *(f16x8*)(&Ks[0][4096 + soff]) = k1v;
        *(f16x8*)(&Vs[0][soff])        = v0v;
        *(f16x8*)(&Vs[0][4096 + soff]) = v1v;
    }
    __syncthreads();

    for (int t = 0; t < 8; ++t) {
        const int cur = t & 1;

        // T14 issue-early: next 128-key tile -> registers
        f16x8 kn0, kn1, vn0, vn1;
        if (t < 7) {
            const f16* Kn = Kp + (t + 1) * 8192;
            const f16* Vn = Vp + (t + 1) * 8192;
            kn0 = *(const f16x8*)(Kn + soff);
            kn1 = *(const f16x8*)(Kn + 4096 + soff);
            vn0 = *(const f16x8*)(Vn + soff);
            vn1 = *(const f16x8*)(Vn + 4096 + soff);
        }

#pragma unroll
        for (int half = 0; half < 2; ++half) {
            const f16* Kc = &Ks[cur][half * 4096];
            const f16* Vc = &Vs[cur][half * 4096];

            // Swapped QK^T: sc = K_frag (A) x Q_frag (B). Lane: query = lo4,
            // keys = f*16 + hi4*4 + {0..3} (consecutive) -> packed b64 stash.
#pragma unroll
            for (int f = 0; f < 4; ++f) {
                const int c = f * 16 + lo4;                 // key row for K read
                f16x8 bk0 = *(const f16x8*)(Kc + c * 64 + ((hi4 ^ (c & 7)) << 3));
                f16x8 bk1 = *(const f16x8*)(Kc + c * 64 + (((4 + hi4) ^ (c & 7)) << 3));
#pragma unroll
                for (int qg = 0; qg < 2; ++qg) {
                    f32x4 sc = (f32x4){0.f, 0.f, 0.f, 0.f};
                    sc = MFMA16(bk0, aq[qg][0], sc);
                    sc = MFMA16(bk1, aq[qg][1], sc);
                    float p0 = __builtin_amdgcn_exp2f(sc[0] - C4_);
                    float p1 = __builtin_amdgcn_exp2f(sc[1] - C4_);
                    float p2 = __builtin_amdgcn_exp2f(sc[2] - C4_);
                    float p3 = __builtin_amdgcn_exp2f(sc[3] - C4_);
                    l[qg] += (p0 + p1) + (p2 + p3);
                    f16x2 a01 = CVT_PK(p0, p1);
                    f16x2 a23 = CVT_PK(p2, p3);
                    f16x4 pv = { a01[0], a01[1], a23[0], a23[1] };
                    *(f16x4*)(Pw + (qg * 16 + lo4) * 72 + f * 16 + hi4 * 4) = pv;
                }
            }
            asm volatile("s_waitcnt lgkmcnt(0)" ::: "memory");
            __builtin_amdgcn_sched_barrier(0);

            // PV: o += P @ V  (P read as A-frag; V rows = d, swizzled cols)
            f16x8 ap[2][2];
#pragma unroll
            for (int qg = 0; qg < 2; ++qg) {
                ap[qg][0] = *(const f16x8*)(Pw + (qg * 16 + lo4) * 72 + hi4 * 8);
                ap[qg][1] = *(const f16x8*)(Pw + (qg * 16 + lo4) * 72 + 32 + hi4 * 8);
            }
#pragma unroll
            for (int dt = 0; dt < 4; ++dt) {
                const int d = dt * 16 + lo4;
                f16x8 bv0 = *(const f16x8*)(Vc + d * 64 + ((hi4 ^ (d & 7)) << 3));
                f16x8 bv1 = *(const f16x8*)(Vc + d * 64 + (((4 + hi4) ^ (d & 7)) << 3));
#pragma unroll
                for (int qg = 0; qg < 2; ++qg) {
                    o[qg][dt] = MFMA16(ap[qg][0], bv0, o[qg][dt]);
                    o[qg][dt] = MFMA16(ap[qg][1], bv1, o[qg][dt]);
                }
            }
        }

        // T14 write-late: registers -> other LDS buffer
        if (t < 7) {
            *(f16x8*)(&Ks[cur ^ 1][soff])        = kn0;
            *(f16x8*)(&Ks[cur ^ 1][4096 + soff]) = kn1;
            *(f16x8*)(&Vs[cur ^ 1][soff])        = vn0;
            *(f16x8*)(&Vs[cur ^ 1][4096 + soff]) = vn1;
        }
        __syncthreads();
    }

    // reduce l across the 4 hi4 groups (query = qg*16 + lo4 per lane)
#pragma unroll
    for (int qg = 0; qg < 2; ++qg) {
        l[qg] += __shfl_xor(l[qg], 16);
        l[qg] += __shfl_xor(l[qg], 32);
    }
    // transpose l to PV output rows via per-wave LDS
    if (lane < 16) {
        Lw[wave][lane]      = l[0];
        Lw[wave][16 + lane] = l[1];
    }
    asm volatile("s_waitcnt lgkmcnt(0)" ::: "memory");
    __builtin_amdgcn_sched_barrier(0);

    const int b = bh >> 3;
    const int h = bh & 7;
#pragma unroll
    for (int qg = 0; qg < 2; ++qg)
#pragma unroll
        for (int r = 0; r < 4; ++r) {
            const float inv = 1.f / Lw[wave][qg * 16 + hi4 * 4 + r];
            const int s_idx = q0 + qg * 16 + hi4 * 4 + r;
            float* op = out + ((size_t)(b * S_ + s_idx)) * D_ + h * HD_;
#pragma unroll
            for (int dt = 0; dt < 4; ++dt)
                op[dt * 16 + lo4] = o[qg][dt][r] * inv;
        }
}

// ---------------------------------------------------------------------------
extern "C" void kernel_launch(void* const* d_in, const int* in_sizes, int n_in,
                              void* d_out, int out_size, void* d_ws, size_t ws_size,
                              hipStream_t stream)
{
    const float* x   = (const float*)d_in[0];
    const float* Wcq = (const float*)d_in[1];
    const float* bcq = (const float*)d_in[2];
    const float* Wck = (const float*)d_in[3];
    const float* bck = (const float*)d_in[4];
    const float* Wcv = (const float*)d_in[5];
    const float* bcv = (const float*)d_in[6];
    const float* Wpq = (const float*)d_in[7];
    const float* bpq = (const float*)d_in[8];
    const float* Wpk = (const float*)d_in[9];
    const float* bpk = (const float*)d_in[10];
    const float* Wpv = (const float*)d_in[11];
    const float* bpv = (const float*)d_in[12];

    f16* ws = (f16*)d_ws;
    f16* xh_t = ws;                                  // 64*16*4096
    f16* Bt_t = xh_t + (size_t)64 * 16 * 4096;       // 12*16*4096
    f16* Qh   = Bt_t + (size_t)12 * 16 * 4096;       // 64*65536
    f16* Kws  = Qh + (size_t)64 * 65536;
    f16* Vws  = Kws + (size_t)64 * 65536;
    float* o = (float*)d_out;

    prep_fused<<<1216, 256, 0, stream>>>(x, xh_t, Wcq, Wck, Wcv, Wpq, Wpk, Wpv, Bt_t);
    qkv_gemm<<<768, 256, 0, stream>>>(xh_t, Bt_t, bcq, bck, bcv, bpq, bpk, bpv,
                                      Qh, Kws, Vws);
    attn_fwd<<<256, 512, 0, stream>>>(Qh, Kws, Vws, o);
}